// Round 1
// baseline (286.940 us; speedup 1.0000x reference)
//
#include <hip/hip_runtime.h>

#define HID 16
#define TLEN 1024

__device__ __forceinline__ float fast_exp2(float a) { return __builtin_amdgcn_exp2f(a); }
__device__ __forceinline__ float fast_rcp(float a)  { return __builtin_amdgcn_rcpf(a); }

// sigmoid(a) = 1 / (1 + e^-a) = rcp(1 + exp2(-a*log2e))
__device__ __forceinline__ float fast_sigmoid(float a) {
    return fast_rcp(1.0f + fast_exp2(a * -1.4426950408889634f));
}
// tanh(a) = 1 - 2/(e^{2a}+1); exp2 overflow/underflow saturate correctly via inf/rcp
__device__ __forceinline__ float fast_tanh(float a) {
    return 1.0f - 2.0f * fast_rcp(1.0f + fast_exp2(a * 2.8853900817779268f));
}

// One lane per (sequence, hidden unit). 64-thread blocks = 1 wave = 4 sequences.
// grid = B/4 = 1024 blocks -> 1024 waves -> 1 wave per SIMD across 256 CUs.
__global__ __launch_bounds__(64) void gru_fused_kernel(
    const float* __restrict__ x,     // [B, T, 1]
    const float* __restrict__ W_ih,  // [48, 1]
    const float* __restrict__ W_hh,  // [48, 16]
    const float* __restrict__ b_ih,  // [48]
    const float* __restrict__ b_hh,  // [48]
    const float* __restrict__ W_fc,  // [5, 16]
    const float* __restrict__ b_fc,  // [5]
    float* __restrict__ out)         // [B, 5]
{
    const int lane = threadIdx.x;      // 0..63
    const int j    = lane & 15;        // hidden unit
    const int s    = lane >> 4;        // sequence-within-wave (0..3)
    const int b    = blockIdx.x * 4 + s;

    // --- per-lane constants (held in registers for the whole kernel) ---
    float wr[HID], wz[HID], wn[HID];
    #pragma unroll
    for (int k = 0; k < HID; ++k) {
        wr[k] = W_hh[(j     ) * HID + k];
        wz[k] = W_hh[(j + 16) * HID + k];
        wn[k] = W_hh[(j + 32) * HID + k];
    }
    const float wih_r = W_ih[j];
    const float wih_z = W_ih[j + 16];
    const float wih_n = W_ih[j + 32];
    const float br  = b_ih[j]      + b_hh[j];        // combined bias for r
    const float bz  = b_ih[j + 16] + b_hh[j + 16];   // combined bias for z
    const float bnx = b_ih[j + 32];                  // input-side bias for n
    const float bnh = b_hh[j + 32];                  // hidden-side bias for n (inside r*)

    const float* __restrict__ xb = x + (size_t)b * TLEN;

    float h = 0.0f;
    // lane j holds x[t0 + j] for the current 16-step chunk
    float xv = xb[j];

    for (int t0 = 0; t0 < TLEN; t0 += 16) {
        // prefetch next chunk (independent of recurrence -> hides HBM latency)
        float xnext = (t0 + 16 < TLEN) ? xb[t0 + 16 + j] : 0.0f;

        #pragma unroll
        for (int i = 0; i < 16; ++i) {
            const float xt = __shfl(xv, i, 16);

            float ar  = __builtin_fmaf(xt, wih_r, br);
            float az  = __builtin_fmaf(xt, wih_z, bz);
            float anx = __builtin_fmaf(xt, wih_n, bnx);
            float gn  = bnh;

            #pragma unroll
            for (int k = 0; k < HID; ++k) {
                const float hk = __shfl(h, k, 16);   // broadcast h_k within 16-lane group
                ar = __builtin_fmaf(wr[k], hk, ar);
                az = __builtin_fmaf(wz[k], hk, az);
                gn = __builtin_fmaf(wn[k], hk, gn);
            }

            const float r  = fast_sigmoid(ar);
            const float z  = fast_sigmoid(az);
            const float n_ = fast_tanh(__builtin_fmaf(r, gn, anx));
            // h = (1-z)*n + z*h = z*(h-n) + n
            h = __builtin_fmaf(z, h - n_, n_);
        }
        xv = xnext;
    }

    // --- epilogue: out[b, c] = sum_j tanh(h_j) * W_fc[c, j] + b_fc[c] ---
    __shared__ float th_s[64];
    th_s[lane] = fast_tanh(h);
    __syncthreads();

    if (j < 5) {
        float acc = b_fc[j];
        #pragma unroll
        for (int k = 0; k < HID; ++k)
            acc = __builtin_fmaf(W_fc[j * HID + k], th_s[s * HID + k], acc);
        out[(size_t)b * 5 + j] = acc;
    }
}

extern "C" void kernel_launch(void* const* d_in, const int* in_sizes, int n_in,
                              void* d_out, int out_size, void* d_ws, size_t ws_size,
                              hipStream_t stream) {
    const float* x    = (const float*)d_in[0];
    const float* W_ih = (const float*)d_in[1];
    const float* W_hh = (const float*)d_in[2];
    const float* b_ih = (const float*)d_in[3];
    const float* b_hh = (const float*)d_in[4];
    const float* W_fc = (const float*)d_in[5];
    const float* b_fc = (const float*)d_in[6];
    float* out = (float*)d_out;

    const int B = in_sizes[0] / TLEN;  // 4096
    gru_fused_kernel<<<dim3(B / 4), dim3(64), 0, stream>>>(
        x, W_ih, W_hh, b_ih, b_hh, W_fc, b_fc, out);
}

// Round 2
// 151.352 us; speedup vs baseline: 1.8958x; 1.8958x over previous
//
#include <hip/hip_runtime.h>

#define HID 16
#define TLEN 1024

typedef float v4f __attribute__((ext_vector_type(4)));

__device__ __forceinline__ float fast_exp2(float a) { return __builtin_amdgcn_exp2f(a); }
__device__ __forceinline__ float fast_rcp(float a)  { return __builtin_amdgcn_rcpf(a); }

// tanh(a) = 1 - 2/(exp2(2a*log2e)+1)  (for the epilogue, unscaled input)
__device__ __forceinline__ float fast_tanh(float a) {
    return __builtin_fmaf(-2.0f, fast_rcp(1.0f + fast_exp2(a * 2.8853900817779268f)), 1.0f);
}

// One lane per (sequence, hidden unit j). 64-thread blocks = 1 wave = 4 sequences.
// grid = B/4 = 1024 blocks -> 1 wave per SIMD across 256 CUs.
__global__ __launch_bounds__(64) void gru_fused_kernel(
    const float* __restrict__ x,     // [B, T, 1]
    const float* __restrict__ W_ih,  // [48, 1]
    const float* __restrict__ W_hh,  // [48, 16]
    const float* __restrict__ b_ih,  // [48]
    const float* __restrict__ b_hh,  // [48]
    const float* __restrict__ W_fc,  // [5, 16]
    const float* __restrict__ b_fc,  // [5]
    float* __restrict__ out)         // [B, 5]
{
    const int lane = threadIdx.x;      // 0..63
    const int j    = lane & 15;        // hidden unit
    const int g    = lane >> 4;        // sequence-within-wave (0..3)
    const int b    = blockIdx.x * 4 + g;

    const float NEG_LOG2E = -1.4426950408889634f;  // sigmoid: rcp(1+exp2(-a*log2e))
    const float TWO_LOG2E =  2.8853900817779268f;  // tanh:    1-2*rcp(1+exp2(2a*log2e))

    // --- per-lane weights, pre-scaled so no multiply sits before exp2 on the
    //     critical path. Held in VGPRs for the whole kernel (v4f => ds_read_b128
    //     results feed v_pk_fma_f32 directly). ---
    v4f wr[4], wz[4], wn[4];
    #pragma unroll
    for (int q = 0; q < 4; ++q) {
        wr[q] = (*(const v4f*)&W_hh[(j     ) * HID + 4 * q]) * NEG_LOG2E;
        wz[q] = (*(const v4f*)&W_hh[(j + 16) * HID + 4 * q]) * NEG_LOG2E;
        wn[q] = (*(const v4f*)&W_hh[(j + 32) * HID + 4 * q]) * TWO_LOG2E;
    }
    const float wih_r = W_ih[j]      * NEG_LOG2E;
    const float wih_z = W_ih[j + 16] * NEG_LOG2E;
    const float wih_n = W_ih[j + 32] * TWO_LOG2E;
    const float br  = (b_ih[j]      + b_hh[j])      * NEG_LOG2E;
    const float bz  = (b_ih[j + 16] + b_hh[j + 16]) * NEG_LOG2E;
    const float bnx = b_ih[j + 32] * TWO_LOG2E;                   // input-side n bias
    const v4f   bnh4 = { b_hh[j + 32] * TWO_LOG2E, 0.f, 0.f, 0.f }; // hidden-side n bias (inside r*)

    // h broadcast buffer: group stride 20 floats (80 B) -> the 4 groups' four
    // ds_read_b128 hit disjoint bank quads; write is <=2-way (free).
    __shared__ float hlds[4 * 20];
    const int hbase = g * 20;

    const float* __restrict__ xb = x + (size_t)b * TLEN;

    float h = 0.0f;
    // current chunk's 16 x values, one full copy per lane (same cacheline per group)
    v4f xc0 = *(const v4f*)(xb +  0);
    v4f xc1 = *(const v4f*)(xb +  4);
    v4f xc2 = *(const v4f*)(xb +  8);
    v4f xc3 = *(const v4f*)(xb + 12);

    for (int t0 = 0; t0 < TLEN; t0 += 16) {
        // prefetch next chunk (uniform branch; independent of the recurrence)
        v4f xn0 = {0,0,0,0}, xn1 = {0,0,0,0}, xn2 = {0,0,0,0}, xn3 = {0,0,0,0};
        if (t0 + 16 < TLEN) {
            xn0 = *(const v4f*)(xb + t0 + 16);
            xn1 = *(const v4f*)(xb + t0 + 20);
            xn2 = *(const v4f*)(xb + t0 + 24);
            xn3 = *(const v4f*)(xb + t0 + 28);
        }

        v4f xcs[4] = { xc0, xc1, xc2, xc3 };
        #pragma unroll
        for (int i = 0; i < 16; ++i) {
            const float xt = xcs[i >> 2][i & 3];   // compile-time indices (unrolled)

            // ---- broadcast h within the 16-lane group via LDS ----
            hlds[hbase + j] = h;
            __builtin_amdgcn_wave_barrier();       // keep write before reads
            v4f h0 = *(v4f*)&hlds[hbase +  0];
            v4f h1 = *(v4f*)&hlds[hbase +  4];
            v4f h2 = *(v4f*)&hlds[hbase +  8];
            v4f h3 = *(v4f*)&hlds[hbase + 12];

            // input-gate terms (off the critical path; xt available early)
            const float rx = __builtin_fmaf(xt, wih_r, br);
            const float zx = __builtin_fmaf(xt, wih_z, bz);
            const float nx = __builtin_fmaf(xt, wih_n, bnx);

            // ---- packed matvec: 3 gates x 4 v4f-FMAs (v_pk_fma_f32) ----
            v4f ar4 = wr[0] * h0;
            v4f az4 = wz[0] * h0;
            v4f an4 = __builtin_elementwise_fma(wn[0], h0, bnh4);
            ar4 = __builtin_elementwise_fma(wr[1], h1, ar4);
            az4 = __builtin_elementwise_fma(wz[1], h1, az4);
            an4 = __builtin_elementwise_fma(wn[1], h1, an4);
            ar4 = __builtin_elementwise_fma(wr[2], h2, ar4);
            az4 = __builtin_elementwise_fma(wz[2], h2, az4);
            an4 = __builtin_elementwise_fma(wn[2], h2, an4);
            ar4 = __builtin_elementwise_fma(wr[3], h3, ar4);
            az4 = __builtin_elementwise_fma(wz[3], h3, az4);
            an4 = __builtin_elementwise_fma(wn[3], h3, an4);

            const float ar  = ((ar4.x + ar4.y) + (ar4.z + ar4.w)) + rx;
            const float az  = ((az4.x + az4.y) + (az4.z + az4.w)) + zx;
            const float ghn = ((an4.x + an4.y) + (an4.z + an4.w));      // includes bnh

            // activations (weights pre-scaled: no mul before exp2)
            const float r  = fast_rcp(1.0f + fast_exp2(ar));
            const float z  = fast_rcp(1.0f + fast_exp2(az));
            const float s  = __builtin_fmaf(r, ghn, nx);
            const float n_ = __builtin_fmaf(-2.0f, fast_rcp(1.0f + fast_exp2(s)), 1.0f);

            // h = (1-z)*n + z*h
            h = __builtin_fmaf(z, h - n_, n_);
        }

        xc0 = xn0; xc1 = xn1; xc2 = xn2; xc3 = xn3;
    }

    // --- epilogue: out[b, c] = sum_j tanh(h_j) * W_fc[c, j] + b_fc[c] ---
    __shared__ float th_s[64];
    th_s[lane] = fast_tanh(h);
    __syncthreads();

    if (j < 5) {
        float acc = b_fc[j];
        #pragma unroll
        for (int k = 0; k < HID; ++k)
            acc = __builtin_fmaf(W_fc[j * HID + k], th_s[g * HID + k], acc);
        out[(size_t)b * 5 + j] = acc;
    }
}

extern "C" void kernel_launch(void* const* d_in, const int* in_sizes, int n_in,
                              void* d_out, int out_size, void* d_ws, size_t ws_size,
                              hipStream_t stream) {
    const float* x    = (const float*)d_in[0];
    const float* W_ih = (const float*)d_in[1];
    const float* W_hh = (const float*)d_in[2];
    const float* b_ih = (const float*)d_in[3];
    const float* b_hh = (const float*)d_in[4];
    const float* W_fc = (const float*)d_in[5];
    const float* b_fc = (const float*)d_in[6];
    float* out = (float*)d_out;

    const int B = in_sizes[0] / TLEN;  // 4096
    gru_fused_kernel<<<dim3(B / 4), dim3(64), 0, stream>>>(
        x, W_ih, W_hh, b_ih, b_hh, W_fc, b_fc, out);
}

// Round 4
// 136.026 us; speedup vs baseline: 2.1094x; 1.1127x over previous
//
#include <hip/hip_runtime.h>

#define HID 16
#define TLEN 1024

typedef float v2f __attribute__((ext_vector_type(2)));
typedef float v4f __attribute__((ext_vector_type(4)));

__device__ __forceinline__ float fast_exp2(float a) { return __builtin_amdgcn_exp2f(a); }
__device__ __forceinline__ float fast_rcp(float a)  { return __builtin_amdgcn_rcpf(a); }

// tanh(a) = 1 - 2/(exp2(2a*log2e)+1)  (epilogue only, unscaled input)
__device__ __forceinline__ float fast_tanh(float a) {
    return __builtin_fmaf(-2.0f, fast_rcp(1.0f + fast_exp2(a * 2.8853900817779268f)), 1.0f);
}

// In-register rotate within each 16-lane row via DPP row_ror:R.
// AMD convention: "rotate right" moves data toward HIGHER lanes, i.e.
//   dst[i] = src[(i - R) & 15]     (cf. rocPRIM shfl_up == row_shr).
template<int R>
__device__ __forceinline__ float ror16(float v) {
    return __builtin_bit_cast(float,
        __builtin_amdgcn_update_dpp(0, __builtin_bit_cast(int, v),
                                    0x120 + R, 0xF, 0xF, true));
}

// One lane per (sequence, hidden unit j). 64-thread blocks = 1 wave = 4 sequences.
// grid = B/4 = 1024 waves -> 1 wave per SIMD across 256 CUs (occupancy is
// structurally capped; all gains must come from shortening the serial chain).
__global__ __launch_bounds__(64, 1) void gru_fused_kernel(
    const float* __restrict__ x,     // [B, T, 1]
    const float* __restrict__ W_ih,  // [48, 1]
    const float* __restrict__ W_hh,  // [48, 16]
    const float* __restrict__ b_ih,  // [48]
    const float* __restrict__ b_hh,  // [48]
    const float* __restrict__ W_fc,  // [5, 16]
    const float* __restrict__ b_fc,  // [5]
    float* __restrict__ out)         // [B, 5]
{
    const int lane = threadIdx.x;      // 0..63
    const int j    = lane & 15;        // hidden unit
    const int g    = lane >> 4;        // sequence-within-wave (0..3)
    const int b    = blockIdx.x * 4 + g;

    const float NEG_LOG2E = -1.4426950408889634f;  // sigmoid: rcp(1+exp2(-a*log2e))
    const float TWO_LOG2E =  2.8853900817779268f;  // tanh:    1-2*rcp(1+exp2(2a*log2e))

    // --- per-lane weights, PRE-ROTATED for the ror-form matvec.
    //     ror16<r>(h) at lane j yields h[(j-r)&15], so pair the weights as
    //     W[j][(j-r)&15]:  ar_j = sum_r W[j][(j-r)&15] * h[(j-r)&15].
    //     Packed in v2f pairs (r=2p, 2p+1) to feed v_pk_fma_f32; pre-scaled
    //     by the exp2 constants (no mul in front of v_exp_f32). ---
    v2f wr2[8], wz2[8], wn2[8];
    #pragma unroll
    for (int p = 0; p < 8; ++p) {
        const int k0 = (j - 2 * p)     & 15;
        const int k1 = (j - 2 * p - 1) & 15;
        wr2[p] = v2f{ W_hh[(j     ) * HID + k0], W_hh[(j     ) * HID + k1] } * NEG_LOG2E;
        wz2[p] = v2f{ W_hh[(j + 16) * HID + k0], W_hh[(j + 16) * HID + k1] } * NEG_LOG2E;
        wn2[p] = v2f{ W_hh[(j + 32) * HID + k0], W_hh[(j + 32) * HID + k1] } * TWO_LOG2E;
    }
    const float wih_r = W_ih[j]      * NEG_LOG2E;
    const float wih_z = W_ih[j + 16] * NEG_LOG2E;
    const float wih_n = W_ih[j + 32] * TWO_LOG2E;
    const float br  = (b_ih[j]      + b_hh[j])      * NEG_LOG2E;
    const float bz  = (b_ih[j + 16] + b_hh[j + 16]) * NEG_LOG2E;
    const float bnx = b_ih[j + 32] * TWO_LOG2E;                     // input-side n bias
    const v2f   bnh2 = { b_hh[j + 32] * TWO_LOG2E, 0.0f };          // hidden-side n bias

    const float* __restrict__ xb = x + (size_t)b * TLEN;

    float h = 0.0f;
    // current chunk's 16 x values, full copy per lane (same cachelines per group)
    v4f xc0 = *(const v4f*)(xb +  0);
    v4f xc1 = *(const v4f*)(xb +  4);
    v4f xc2 = *(const v4f*)(xb +  8);
    v4f xc3 = *(const v4f*)(xb + 12);

    for (int t0 = 0; t0 < TLEN; t0 += 16) {
        // prefetch next chunk (independent of the recurrence)
        v4f xn0 = {0,0,0,0}, xn1 = {0,0,0,0}, xn2 = {0,0,0,0}, xn3 = {0,0,0,0};
        if (t0 + 16 < TLEN) {
            xn0 = *(const v4f*)(xb + t0 + 16);
            xn1 = *(const v4f*)(xb + t0 + 20);
            xn2 = *(const v4f*)(xb + t0 + 24);
            xn3 = *(const v4f*)(xb + t0 + 28);
        }

        const v4f xcs[4] = { xc0, xc1, xc2, xc3 };
        #pragma unroll
        for (int i = 0; i < 16; ++i) {
            const float xt = xcs[i >> 2][i & 3];   // compile-time indices

            // input-gate terms (off the critical path)
            const float rx = __builtin_fmaf(xt, wih_r, br);
            const float zx = __builtin_fmaf(xt, wih_z, bz);
            const float nx = __builtin_fmaf(xt, wih_n, bnx);

            // ---- 15 independent DPP rotations of h (replaces LDS gather) ----
            const float q1  = ror16<1>(h),  q2  = ror16<2>(h),  q3  = ror16<3>(h);
            const float q4  = ror16<4>(h),  q5  = ror16<5>(h),  q6  = ror16<6>(h);
            const float q7  = ror16<7>(h),  q8  = ror16<8>(h),  q9  = ror16<9>(h);
            const float q10 = ror16<10>(h), q11 = ror16<11>(h), q12 = ror16<12>(h);
            const float q13 = ror16<13>(h), q14 = ror16<14>(h), q15 = ror16<15>(h);

            const v2f h2_0 = { h,   q1  }, h2_1 = { q2,  q3  };
            const v2f h2_2 = { q4,  q5  }, h2_3 = { q6,  q7  };
            const v2f h2_4 = { q8,  q9  }, h2_5 = { q10, q11 };
            const v2f h2_6 = { q12, q13 }, h2_7 = { q14, q15 };

            // ---- packed matvec: 2 chains of depth 4 per gate (v_pk_fma_f32) ----
            v2f ra = wr2[0] * h2_0;
            v2f za = wz2[0] * h2_0;
            v2f na = __builtin_elementwise_fma(wn2[0], h2_0, bnh2);
            ra = __builtin_elementwise_fma(wr2[1], h2_1, ra);
            za = __builtin_elementwise_fma(wz2[1], h2_1, za);
            na = __builtin_elementwise_fma(wn2[1], h2_1, na);
            ra = __builtin_elementwise_fma(wr2[2], h2_2, ra);
            za = __builtin_elementwise_fma(wz2[2], h2_2, za);
            na = __builtin_elementwise_fma(wn2[2], h2_2, na);
            ra = __builtin_elementwise_fma(wr2[3], h2_3, ra);
            za = __builtin_elementwise_fma(wz2[3], h2_3, za);
            na = __builtin_elementwise_fma(wn2[3], h2_3, na);

            v2f rb = wr2[4] * h2_4;
            v2f zb = wz2[4] * h2_4;
            v2f nb = wn2[4] * h2_4;
            rb = __builtin_elementwise_fma(wr2[5], h2_5, rb);
            zb = __builtin_elementwise_fma(wz2[5], h2_5, zb);
            nb = __builtin_elementwise_fma(wn2[5], h2_5, nb);
            rb = __builtin_elementwise_fma(wr2[6], h2_6, rb);
            zb = __builtin_elementwise_fma(wz2[6], h2_6, zb);
            nb = __builtin_elementwise_fma(wn2[6], h2_6, nb);
            rb = __builtin_elementwise_fma(wr2[7], h2_7, rb);
            zb = __builtin_elementwise_fma(wz2[7], h2_7, zb);
            nb = __builtin_elementwise_fma(wn2[7], h2_7, nb);

            const v2f rt = ra + rb;
            const v2f zt = za + zb;
            const v2f nt = na + nb;
            const float ar  = (rt.x + rt.y) + rx;
            const float az  = (zt.x + zt.y) + zx;
            const float ghn = (nt.x + nt.y);          // includes bnh

            // activations (weights pre-scaled: no mul before exp2)
            const float r  = fast_rcp(1.0f + fast_exp2(ar));
            const float z  = fast_rcp(1.0f + fast_exp2(az));
            const float s  = __builtin_fmaf(r, ghn, nx);
            const float n_ = __builtin_fmaf(-2.0f, fast_rcp(1.0f + fast_exp2(s)), 1.0f);

            // h = (1-z)*n + z*h
            h = __builtin_fmaf(z, h - n_, n_);
        }

        xc0 = xn0; xc1 = xn1; xc2 = xn2; xc3 = xn3;
    }

    // --- epilogue: out[b, c] = sum_j tanh(h_j) * W_fc[c, j] + b_fc[c] ---
    __shared__ float th_s[64];
    th_s[lane] = fast_tanh(h);
    __syncthreads();

    if (j < 5) {
        float acc = b_fc[j];
        #pragma unroll
        for (int k = 0; k < HID; ++k)
            acc = __builtin_fmaf(W_fc[j * HID + k], th_s[g * HID + k], acc);
        out[(size_t)b * 5 + j] = acc;
    }
}

extern "C" void kernel_launch(void* const* d_in, const int* in_sizes, int n_in,
                              void* d_out, int out_size, void* d_ws, size_t ws_size,
                              hipStream_t stream) {
    const float* x    = (const float*)d_in[0];
    const float* W_ih = (const float*)d_in[1];
    const float* W_hh = (const float*)d_in[2];
    const float* b_ih = (const float*)d_in[3];
    const float* b_hh = (const float*)d_in[4];
    const float* W_fc = (const float*)d_in[5];
    const float* b_fc = (const float*)d_in[6];
    float* out = (float*)d_out;

    const int B = in_sizes[0] / TLEN;  // 4096
    gru_fused_kernel<<<dim3(B / 4), dim3(64), 0, stream>>>(
        x, W_ih, W_hh, b_ih, b_hh, W_fc, b_fc, out);
}